// Round 1
// baseline (3258.400 us; speedup 1.0000x reference)
//
#include <hip/hip_runtime.h>
#include <math.h>

#define B_    64
#define W_    128
#define N_    40
#define FIN   66
#define HID   100
#define NEWD  71
#define G4    400   // 4*HID
#define MSEQ  10    // sequences per block
#define NBLK  256   // 2560 / MSEQ
#define NTHR  512
#define E_    240

__device__ __forceinline__ float sigmoidf_(float x) { return 1.0f / (1.0f + expf(-x)); }

// ---------------------------------------------------------------------------
// Kernel A: fused feature-build + 128-step recurrent scan + lin head.
// One block = MSEQ sequences. State (h,c) lives in LDS, weights stream from L2
// (Wd_w staged in LDS, padded stride 101 to avoid bank conflicts).
// Thread roles per step:
//   t < 400        : gate rows j0=t&~1, j0+1  for 5 sequences (t&1 selects half)
//   448 <= t < 512 : Wd rows (t-448) and (t-448+64) for all 10 sequences
// ---------------------------------------------------------------------------
__global__ __launch_bounds__(NTHR, 1)
void lstm_kernel(const float* __restrict__ X, const float* __restrict__ ts,
                 const float* __restrict__ emb_pos, const float* __restrict__ emb_team,
                 const float* __restrict__ Wall_w, const float* __restrict__ Wall_b,
                 const float* __restrict__ Uall_w, const float* __restrict__ Uall_b,
                 const float* __restrict__ Wd_w,   const float* __restrict__ Wd_b,
                 const float* __restrict__ lin_w,  const float* __restrict__ lin_b,
                 float* __restrict__ nodes)
{
    __shared__ float h_t[HID][MSEQ];      // [k][m]
    __shared__ float c_t[HID][MSEQ];
    __shared__ float xe_t[NEWD][MSEQ];
    __shared__ float gates_s[G4 * MSEQ];  // sigmoid(gates), index j*10+m
    __shared__ float cs1_s[HID * MSEQ];   // tanh(c@Wd^T+b), index i*10+m
    __shared__ float t_sh[MSEQ];
    __shared__ float wd_l[HID * 101];     // Wd_w staged, padded stride

    const int t  = threadIdx.x;
    const int r0 = blockIdx.x * MSEQ;

    // stage Wd_w into LDS (stride 101)
    for (int i = t; i < HID * HID; i += NTHR) {
        int r = i / HID, c = i % HID;
        wd_l[r * 101 + c] = Wd_w[i];
    }
    // zero state
    for (int i = t; i < HID * MSEQ; i += NTHR) {
        (&h_t[0][0])[i] = 0.0f;
        (&c_t[0][0])[i] = 0.0f;
    }

    // ---- per-thread load-phase roles (hoisted) ----
    // role 0: idx0 = t  (always a continuous-feature slot, m0 in [0,7])
    const int m0 = t / FIN, f0 = t % FIN;
    const int  r_0 = r0 + m0;
    const float* xptr0 = X + ((size_t)(r_0 / N_) * W_ * N_ + (r_0 % N_)) * FIN + f0;
    const bool do0 = (f0 < 64);

    // role 1: idx1 = t + 512
    int kind1 = 0;              // 0 none, 1 cont, 2 emb, 3 ts
    int m1 = 0, f1 = 0, me = 0, mt = 0;
    const float* xptr1 = nullptr;
    const float* xcat  = nullptr;
    const float* tsp   = nullptr;
    if (t < 148) {
        int idx1 = t + NTHR;
        m1 = idx1 / FIN; f1 = idx1 % FIN;
        int r = r0 + m1;
        xptr1 = X + ((size_t)(r / N_) * W_ * N_ + (r % N_)) * FIN + f1;
        kind1 = (f1 < 64) ? 1 : 0;
    } else if (t < 158) {
        me = t - 148;
        int r = r0 + me;
        xcat = X + ((size_t)(r / N_) * W_ * N_ + (r % N_)) * FIN;
        kind1 = 2;
    } else if (t < 168) {
        mt = t - 158;
        int r = r0 + mt;
        tsp = ts + (size_t)(r / N_) * W_ * N_ + (r % N_);
        kind1 = 3;
    }

    // ---- per-thread compute-phase constants (hoisted) ----
    int   j0 = 0, mb = 0;
    float bias0 = 0.f, bias1 = 0.f;
    const float* w0 = nullptr; const float* w1 = nullptr;
    const float* u0 = nullptr; const float* u1 = nullptr;
    if (t < 400) {
        j0 = t & ~1;               // even row
        mb = 5 * (t & 1);
        w0 = Wall_w + (size_t)j0 * HID;  w1 = w0 + HID;
        u0 = Uall_w + (size_t)j0 * NEWD; u1 = u0 + NEWD;
        bias0 = Wall_b[j0]     + Uall_b[j0];
        bias1 = Wall_b[j0 + 1] + Uall_b[j0 + 1];
    }
    float wdb0 = 0.f, wdb1 = 0.f;
    if (t >= 448) {
        int i0 = t - 448;
        wdb0 = Wd_b[i0];
        if (i0 + 64 < HID) wdb1 = Wd_b[i0 + 64];
    }

    for (int wstep = 0; wstep < W_; ++wstep) {
        // ---------------- load phase ----------------
        const size_t xw = (size_t)wstep * (N_ * FIN);
        if (do0) xe_t[f0][m0] = xptr0[xw];
        if (kind1 == 1) {
            xe_t[f1][m1] = xptr1[xw];
        } else if (kind1 == 2) {
            int ip = (int)xcat[xw + 64];
            int it = (int)xcat[xw + 65];
            int   sp = ip > 0 ? ip - 1 : 0;  float fp = ip > 0 ? 1.f : 0.f;
            int   st = it > 0 ? it - 1 : 0;  float ft = it > 0 ? 1.f : 0.f;
            #pragma unroll
            for (int q = 0; q < 4; ++q) xe_t[64 + q][me] = emb_pos[sp * 4 + q] * fp;
            #pragma unroll
            for (int q = 0; q < 3; ++q) xe_t[68 + q][me] = emb_team[st * 3 + q] * ft;
        } else if (kind1 == 3) {
            t_sh[mt] = tsp[(size_t)wstep * N_];
        }
        __syncthreads();

        // ---------------- compute phase ----------------
        if (t < 400) {
            float acc0[5], acc1[5];
            #pragma unroll
            for (int q = 0; q < 5; ++q) { acc0[q] = bias0; acc1[q] = bias1; }
            #pragma unroll 4
            for (int k = 0; k < HID; ++k) {
                float a0 = w0[k], a1 = w1[k];
                #pragma unroll
                for (int q = 0; q < 5; ++q) {
                    float hv = h_t[k][mb + q];
                    acc0[q] += a0 * hv; acc1[q] += a1 * hv;
                }
            }
            #pragma unroll 4
            for (int k = 0; k < NEWD; ++k) {
                float a0 = u0[k], a1 = u1[k];
                #pragma unroll
                for (int q = 0; q < 5; ++q) {
                    float xv = xe_t[k][mb + q];
                    acc0[q] += a0 * xv; acc1[q] += a1 * xv;
                }
            }
            #pragma unroll
            for (int q = 0; q < 5; ++q) {
                gates_s[(size_t)j0 * MSEQ + mb + q]       = sigmoidf_(acc0[q]);
                gates_s[(size_t)(j0 + 1) * MSEQ + mb + q] = sigmoidf_(acc1[q]);
            }
        } else if (t >= 448) {
            int i0 = t - 448;
            {
                const float* wr = wd_l + i0 * 101;
                float acc[MSEQ];
                #pragma unroll
                for (int m = 0; m < MSEQ; ++m) acc[m] = wdb0;
                #pragma unroll 4
                for (int k = 0; k < HID; ++k) {
                    float a = wr[k];
                    #pragma unroll
                    for (int m = 0; m < MSEQ; ++m) acc[m] += a * c_t[k][m];
                }
                #pragma unroll
                for (int m = 0; m < MSEQ; ++m) cs1_s[i0 * MSEQ + m] = tanhf(acc[m]);
            }
            int i1 = i0 + 64;
            if (i1 < HID) {
                const float* wr = wd_l + i1 * 101;
                float acc[MSEQ];
                #pragma unroll
                for (int m = 0; m < MSEQ; ++m) acc[m] = wdb1;
                #pragma unroll 4
                for (int k = 0; k < HID; ++k) {
                    float a = wr[k];
                    #pragma unroll
                    for (int m = 0; m < MSEQ; ++m) acc[m] += a * c_t[k][m];
                }
                #pragma unroll
                for (int m = 0; m < MSEQ; ++m) cs1_s[i1 * MSEQ + m] = tanhf(acc[m]);
            }
        }
        __syncthreads();

        // ---------------- update phase ----------------
        for (int idx = t; idx < HID * MSEQ; idx += NTHR) {
            int i = idx / MSEQ, m = idx % MSEQ;
            float f   = gates_s[idx];
            float ig  = gates_s[idx + 1000];
            float o   = gates_s[idx + 2000];
            float ct  = gates_s[idx + 3000];
            float cs1 = cs1_s[idx];
            float cold = c_t[i][m];
            float tsv  = t_sh[m];
            float cadj = cold - cs1 + cs1 * tsv;
            float cn = f * cadj + ig * ct;
            c_t[i][m] = cn;
            h_t[i][m] = o * tanhf(cn);
        }
        __syncthreads();
    }

    // ---------------- lin head: nodes = relu(h @ lin_w^T + lin_b) ----------------
    for (int idx = t; idx < HID * MSEQ; idx += NTHR) {
        int i = idx / MSEQ, m = idx % MSEQ;
        const float* lr = lin_w + (size_t)i * HID;
        float acc = lin_b[i];
        for (int k = 0; k < HID; ++k) acc += lr[k] * h_t[k][m];
        nodes[(size_t)(r0 + m) * HID + i] = fmaxf(acc, 0.0f);
    }
}

// ---------------------------------------------------------------------------
// Kernel B: per-batch GraphSAGE x2 + output head, all in LDS.
// ---------------------------------------------------------------------------
__global__ __launch_bounds__(256, 1)
void sage_kernel(const float* __restrict__ nodes, const int* __restrict__ edge,
                 const float* __restrict__ s1l, const float* __restrict__ s1lb,
                 const float* __restrict__ s1r,
                 const float* __restrict__ s2l, const float* __restrict__ s2lb,
                 const float* __restrict__ s2r,
                 const float* __restrict__ ow,  const float* __restrict__ ob,
                 float* __restrict__ out)
{
    __shared__ float nd[N_ * HID];
    __shared__ float agg[N_ * HID];
    __shared__ float g1[N_ * 64];
    __shared__ float agg2[N_ * 64];
    __shared__ float g2[N_ * 32];
    __shared__ float deg[N_];
    __shared__ float invdeg[N_];

    const int t = threadIdx.x;
    const int b = blockIdx.x;
    const int* esrc = edge;
    const int* edst = edge + E_;

    for (int i = t; i < N_ * HID; i += 256) {
        nd[i]  = nodes[(size_t)b * N_ * HID + i];
        agg[i] = 0.0f;
    }
    for (int i = t; i < N_; i += 256) deg[i] = 0.0f;
    __syncthreads();

    if (t < E_) atomicAdd(&deg[edst[t]], 1.0f);
    for (int i = t; i < E_ * HID; i += 256) {
        int e = i / HID, k = i % HID;
        atomicAdd(&agg[edst[e] * HID + k], nd[esrc[e] * HID + k]);
    }
    __syncthreads();
    for (int i = t; i < N_; i += 256) invdeg[i] = 1.0f / fmaxf(deg[i], 1.0f);
    __syncthreads();

    // sage1 -> g1 (N x 64), relu
    for (int idx = t; idx < N_ * 64; idx += 256) {
        int n = idx / 64, i = idx % 64;
        const float* lr = s1l + (size_t)i * HID;
        const float* rr = s1r + (size_t)i * HID;
        float id = invdeg[n];
        float acc = s1lb[i];
        for (int k = 0; k < HID; ++k)
            acc += lr[k] * (agg[n * HID + k] * id) + rr[k] * nd[n * HID + k];
        g1[idx] = fmaxf(acc, 0.0f);
    }
    __syncthreads();
    for (int i = t; i < N_ * 64; i += 256) agg2[i] = 0.0f;
    __syncthreads();
    for (int i = t; i < E_ * 64; i += 256) {
        int e = i / 64, k = i % 64;
        atomicAdd(&agg2[edst[e] * 64 + k], g1[esrc[e] * 64 + k]);
    }
    __syncthreads();

    // sage2 -> g2 (N x 32), relu
    for (int idx = t; idx < N_ * 32; idx += 256) {
        int n = idx / 32, i = idx % 32;
        const float* lr = s2l + (size_t)i * 64;
        const float* rr = s2r + (size_t)i * 64;
        float id = invdeg[n];
        float acc = s2lb[i];
        for (int k = 0; k < 64; ++k)
            acc += lr[k] * (agg2[n * 64 + k] * id) + rr[k] * g1[n * 64 + k];
        g2[idx] = fmaxf(acc, 0.0f);
    }
    __syncthreads();

    // output head -> (N, 2), relu
    for (int idx = t; idx < N_ * 2; idx += 256) {
        int n = idx / 2, c = idx % 2;
        const float* wr = ow + (size_t)c * 32;
        float acc = ob[c];
        for (int k = 0; k < 32; ++k) acc += wr[k] * g2[n * 32 + k];
        out[((size_t)b * N_ + n) * 2 + c] = fmaxf(acc, 0.0f);
    }
}

extern "C" void kernel_launch(void* const* d_in, const int* in_sizes, int n_in,
                              void* d_out, int out_size, void* d_ws, size_t ws_size,
                              hipStream_t stream) {
    const float* X        = (const float*)d_in[0];
    const float* ts       = (const float*)d_in[1];
    const int*   edge     = (const int*)  d_in[2];
    const float* emb_pos  = (const float*)d_in[3];
    const float* emb_team = (const float*)d_in[4];
    const float* Wall_w   = (const float*)d_in[5];
    const float* Wall_b   = (const float*)d_in[6];
    const float* Uall_w   = (const float*)d_in[7];
    const float* Uall_b   = (const float*)d_in[8];
    const float* Wd_w     = (const float*)d_in[9];
    const float* Wd_b     = (const float*)d_in[10];
    const float* lin_w    = (const float*)d_in[11];
    const float* lin_b    = (const float*)d_in[12];
    const float* s1l      = (const float*)d_in[13];
    const float* s1lb     = (const float*)d_in[14];
    const float* s1r      = (const float*)d_in[15];
    const float* s2l      = (const float*)d_in[16];
    const float* s2lb     = (const float*)d_in[17];
    const float* s2r      = (const float*)d_in[18];
    const float* ow       = (const float*)d_in[19];
    const float* ob       = (const float*)d_in[20];

    float* nodes = (float*)d_ws;   // (2560, 100) fp32 = 1 MB scratch

    lstm_kernel<<<NBLK, NTHR, 0, stream>>>(X, ts, emb_pos, emb_team,
                                           Wall_w, Wall_b, Uall_w, Uall_b,
                                           Wd_w, Wd_b, lin_w, lin_b, nodes);
    sage_kernel<<<B_, 256, 0, stream>>>(nodes, edge, s1l, s1lb, s1r,
                                        s2l, s2lb, s2r, ow, ob, (float*)d_out);
}

// Round 2
// 2231.839 us; speedup vs baseline: 1.4600x; 1.4600x over previous
//
#include <hip/hip_runtime.h>
#include <math.h>

#define B_    64
#define W_    128
#define N_    40
#define FIN   66
#define HID   100
#define NEWD  71
#define G4    400   // 4*HID
#define MSEQ  10    // sequences per block
#define NBLK  256   // 2560 / MSEQ
#define NTHR  1024  // 16 waves
#define E_    240
#define WSTR  176   // padded combined weight stride (100 Wall + 71 Uall + 5 pad)

__device__ __forceinline__ float sig_(float x) {
    return __builtin_amdgcn_rcpf(1.0f + __expf(-x));
}
__device__ __forceinline__ float tanh_(float x) {
    return fmaf(2.0f, __builtin_amdgcn_rcpf(1.0f + __expf(-2.0f * x)), -1.0f);
}

// ---------------------------------------------------------------------------
// Repack: Wcomb[j][0:100)=Wall_w[j], [100:171)=Uall_w[j], [171:176)=0  (16B rows)
//         WdT[k][i] = Wd_w[i][k]   (transposed for coalesced decay reads)
// ---------------------------------------------------------------------------
__global__ void repack_kernel(const float* __restrict__ Wall_w,
                              const float* __restrict__ Uall_w,
                              const float* __restrict__ Wd_w,
                              float* __restrict__ Wcomb,
                              float* __restrict__ WdT)
{
    int idx = blockIdx.x * blockDim.x + threadIdx.x;
    if (idx < G4 * WSTR) {
        int j = idx / WSTR, k = idx % WSTR;
        float v = 0.0f;
        if (k < HID)            v = Wall_w[j * HID + k];
        else if (k < HID + NEWD) v = Uall_w[j * NEWD + (k - HID)];
        Wcomb[idx] = v;
    } else if (idx < G4 * WSTR + HID * HID) {
        int j2 = idx - G4 * WSTR;
        int k = j2 / HID, i = j2 % HID;
        WdT[j2] = Wd_w[i * HID + k];
    }
}

// ---------------------------------------------------------------------------
// LSTM kernel: 256 blocks x 1024 threads (16 waves/CU).
// Waves 0..13 (t<896): gate GEMM. wave parity = K-half (kh).
//   pair p = (wave>>1)*32 + (lane>>1)  in [0,224), clamped to 199 (dup, benign)
//   rows j0=2p, j0+1 ; seq-half mb = 5*(lane&1)
//   kh0: K=[0,88) (h only). kh1: K=[88,100) h + xe[0,72) (row 71 = zero pad).
// Waves 14,15 (t>=896): decay rows (clamped dup >=100), all 10 seqs, K=100.
// Per step: C(FMA + prefetch issue) | A | G(combine+sigmoid, xe_next write) |
//           B | U(state update) | C'
// ---------------------------------------------------------------------------
__global__ __launch_bounds__(NTHR, 4)
void lstm_kernel(const float* __restrict__ X, const float* __restrict__ ts,
                 const float* __restrict__ emb_pos, const float* __restrict__ emb_team,
                 const float* __restrict__ Wcomb, const float* __restrict__ WdT,
                 const float* __restrict__ Wall_b, const float* __restrict__ Uall_b,
                 const float* __restrict__ Wd_b,
                 const float* __restrict__ lin_w,  const float* __restrict__ lin_b,
                 float* __restrict__ nodes)
{
    __shared__ float h_s[HID * MSEQ];          // k*10+m
    __shared__ float c_s[HID * MSEQ];
    __shared__ float xe_s[2][72 * MSEQ];       // kx*10+m (row 71 = zero pad)
    __shared__ float gates_s[G4 * MSEQ];       // j*10+m (partials then sigmoid)
    __shared__ float cs1_s[HID * MSEQ];
    __shared__ float ts_s[2][MSEQ];

    const int t  = threadIdx.x;
    const int r0 = blockIdx.x * MSEQ;

    // ---- init ----
    for (int i = t; i < HID * MSEQ; i += NTHR) { h_s[i] = 0.0f; c_s[i] = 0.0f; }
    if (t < MSEQ) { xe_s[0][71 * MSEQ + t] = 0.0f; xe_s[1][71 * MSEQ + t] = 0.0f; }

    // ---- roles ----
    const bool isGate = (t < 896);
    const int wv = t >> 6, lane = t & 63;
    int kh = 0, j0 = 0, mb = 0;
    float bias0 = 0.f, bias1 = 0.f;
    const float4 *w0v = nullptr, *w1v = nullptr;
    if (isGate) {
        kh = wv & 1;
        int p = (wv >> 1) * 32 + (lane >> 1);
        mb = 5 * (lane & 1);
        int pe = (p < 200) ? p : 199;
        j0 = 2 * pe;
        w0v = (const float4*)(Wcomb + (size_t)j0 * WSTR + kh * 88);
        w1v = (const float4*)(Wcomb + (size_t)(j0 + 1) * WSTR + kh * 88);
        if (kh == 0) {
            bias0 = Wall_b[j0]     + Uall_b[j0];
            bias1 = Wall_b[j0 + 1] + Uall_b[j0 + 1];
        }
    }
    int drow = 0; float wdb = 0.f;
    if (!isGate) {
        int l2 = t - 896;
        drow = (l2 < HID) ? l2 : (HID - 1);
        wdb = Wd_b[drow];
    }

    // X/emb/ts load roles
    const float* xptr = nullptr;
    if (t < 640) {
        int m = t >> 6, f = t & 63;
        int r = r0 + m, b = r / N_, n = r % N_;
        xptr = X + ((size_t)b * W_ * N_ + n) * FIN + f;   // + w*N_*FIN per step
    }
    const float* xcat = nullptr; const float* tsp = nullptr;
    int me = 0, mt = 0;
    if (t >= 1004 && t < 1014) {
        me = t - 1004;
        int r = r0 + me, b = r / N_, n = r % N_;
        xcat = X + ((size_t)b * W_ * N_ + n) * FIN;
    } else if (t >= 1014) {
        mt = t - 1014;
        int r = r0 + mt, b = r / N_, n = r % N_;
        tsp = ts + (size_t)b * W_ * N_ + n;
    }

    // ---- prologue: fill xe/ts buffer 0 (w=0) ----
    if (xptr) xe_s[0][(t & 63) * MSEQ + (t >> 6)] = xptr[0];
    if (xcat) {
        float c0f = xcat[64], c1f = xcat[65];
        int ip = (int)c0f, itm = (int)c1f;
        int   sp = ip > 0 ? ip - 1 : 0;  float fp  = ip > 0 ? 1.f : 0.f;
        int   st = itm > 0 ? itm - 1 : 0; float ft_ = itm > 0 ? 1.f : 0.f;
        #pragma unroll
        for (int q = 0; q < 4; ++q) xe_s[0][(64 + q) * MSEQ + me] = emb_pos[sp * 4 + q] * fp;
        #pragma unroll
        for (int q = 0; q < 3; ++q) xe_s[0][(68 + q) * MSEQ + me] = emb_team[st * 3 + q] * ft_;
    }
    if (tsp) ts_s[0][mt] = tsp[0];
    __syncthreads();

    // ---- main 128-step loop ----
    for (int w = 0; w < W_; ++w) {
        const int cur = w & 1, nxt = cur ^ 1;
        const bool pf = (w + 1 < W_);

        // ===== phase C: prefetch issue + FMA =====
        float xv = 0.f, c0f = 0.f, c1f = 0.f, tv = 0.f;
        if (pf) {
            const size_t off = (size_t)(w + 1) * (N_ * FIN);
            if (xptr) xv  = xptr[off];
            if (xcat) { c0f = xcat[off + 64]; c1f = xcat[off + 65]; }
            if (tsp)  tv  = tsp[(size_t)(w + 1) * N_];
        }

        float acc0[5], acc1[5];
        #pragma unroll
        for (int s = 0; s < 5; ++s) { acc0[s] = 0.f; acc1[s] = 0.f; }

        if (isGate) {
            const float* hs = h_s + mb;
            const float* xs = xe_s[cur] + mb;
            if (kh == 0) {
                #pragma unroll 2
                for (int q = 0; q < 22; ++q) {
                    float4 a0 = w0v[q], a1 = w1v[q];
                    const float* A0 = (const float*)&a0;
                    const float* A1 = (const float*)&a1;
                    #pragma unroll
                    for (int e = 0; e < 4; ++e) {
                        const int k = 4 * q + e;
                        #pragma unroll
                        for (int s = 0; s < 5; ++s) {
                            float hv = hs[k * MSEQ + s];
                            acc0[s] = fmaf(A0[e], hv, acc0[s]);
                            acc1[s] = fmaf(A1[e], hv, acc1[s]);
                        }
                    }
                }
            } else {
                #pragma unroll
                for (int q = 0; q < 3; ++q) {       // K = 88..99 from h
                    float4 a0 = w0v[q], a1 = w1v[q];
                    const float* A0 = (const float*)&a0;
                    const float* A1 = (const float*)&a1;
                    #pragma unroll
                    for (int e = 0; e < 4; ++e) {
                        const int k = 88 + 4 * q + e;
                        #pragma unroll
                        for (int s = 0; s < 5; ++s) {
                            float hv = hs[k * MSEQ + s];
                            acc0[s] = fmaf(A0[e], hv, acc0[s]);
                            acc1[s] = fmaf(A1[e], hv, acc1[s]);
                        }
                    }
                }
                #pragma unroll 2
                for (int q = 3; q < 21; ++q) {      // K = 100..171 from xe (71 = pad0)
                    float4 a0 = w0v[q], a1 = w1v[q];
                    const float* A0 = (const float*)&a0;
                    const float* A1 = (const float*)&a1;
                    #pragma unroll
                    for (int e = 0; e < 4; ++e) {
                        const int kx = 4 * q + e - 12;
                        #pragma unroll
                        for (int s = 0; s < 5; ++s) {
                            float xvv = xs[kx * MSEQ + s];
                            acc0[s] = fmaf(A0[e], xvv, acc0[s]);
                            acc1[s] = fmaf(A1[e], xvv, acc1[s]);
                        }
                    }
                }
                // write raw partials into gates_s (combined by kh0 after barrier)
                #pragma unroll
                for (int s = 0; s < 5; ++s) {
                    gates_s[j0 * MSEQ + mb + s]       = acc0[s];
                    gates_s[(j0 + 1) * MSEQ + mb + s] = acc1[s];
                }
            }
        } else {
            // decay: cs1 = tanh(c @ Wd^T + b)
            float acc[MSEQ];
            #pragma unroll
            for (int m = 0; m < MSEQ; ++m) acc[m] = wdb;
            const float* wdp = WdT + drow;
            #pragma unroll 2
            for (int k = 0; k < HID; ++k) {
                float a = wdp[k * HID];
                #pragma unroll
                for (int m = 0; m < MSEQ; ++m)
                    acc[m] = fmaf(a, c_s[k * MSEQ + m], acc[m]);
            }
            #pragma unroll
            for (int m = 0; m < MSEQ; ++m) cs1_s[drow * MSEQ + m] = tanh_(acc[m]);
        }
        __syncthreads();   // A

        // ===== phase G: combine + sigmoid ; xe_next writes =====
        if (isGate && kh == 0) {
            #pragma unroll
            for (int s = 0; s < 5; ++s) {
                float g0 = acc0[s] + bias0 + gates_s[j0 * MSEQ + mb + s];
                float g1 = acc1[s] + bias1 + gates_s[(j0 + 1) * MSEQ + mb + s];
                gates_s[j0 * MSEQ + mb + s]       = sig_(g0);
                gates_s[(j0 + 1) * MSEQ + mb + s] = sig_(g1);
            }
        }
        if (pf) {
            if (xptr) xe_s[nxt][(t & 63) * MSEQ + (t >> 6)] = xv;
            if (xcat) {
                int ip = (int)c0f, itm = (int)c1f;
                int   sp = ip > 0 ? ip - 1 : 0;  float fp  = ip > 0 ? 1.f : 0.f;
                int   st = itm > 0 ? itm - 1 : 0; float ft_ = itm > 0 ? 1.f : 0.f;
                #pragma unroll
                for (int q = 0; q < 4; ++q) xe_s[nxt][(64 + q) * MSEQ + me] = emb_pos[sp * 4 + q] * fp;
                #pragma unroll
                for (int q = 0; q < 3; ++q) xe_s[nxt][(68 + q) * MSEQ + me] = emb_team[st * 3 + q] * ft_;
            }
            if (tsp) ts_s[nxt][mt] = tv;
        }
        __syncthreads();   // B

        // ===== phase U: state update =====
        if (t < HID * MSEQ) {
            const int m = t % MSEQ;
            float f   = gates_s[t];
            float ig  = gates_s[t + 1000];
            float o   = gates_s[t + 2000];
            float ct  = gates_s[t + 3000];
            float cs1 = cs1_s[t];
            float cold = c_s[t];
            float tsv  = ts_s[cur][m];
            float cadj = cold - cs1 + cs1 * tsv;
            float cn = f * cadj + ig * ct;
            c_s[t] = cn;
            h_s[t] = o * tanh_(cn);
        }
        __syncthreads();   // C
    }

    // ---- lin head: nodes = relu(h @ lin_w^T + lin_b) ----
    if (t < HID * MSEQ) {
        const int i = t / MSEQ, m = t % MSEQ;
        const float* lr = lin_w + (size_t)i * HID;
        float acc = lin_b[i];
        for (int k = 0; k < HID; ++k) acc = fmaf(lr[k], h_s[k * MSEQ + m], acc);
        nodes[(size_t)(r0 + m) * HID + i] = fmaxf(acc, 0.0f);
    }
}

// ---------------------------------------------------------------------------
// Kernel B: per-batch GraphSAGE x2 + output head, all in LDS. (unchanged)
// ---------------------------------------------------------------------------
__global__ __launch_bounds__(256, 1)
void sage_kernel(const float* __restrict__ nodes, const int* __restrict__ edge,
                 const float* __restrict__ s1l, const float* __restrict__ s1lb,
                 const float* __restrict__ s1r,
                 const float* __restrict__ s2l, const float* __restrict__ s2lb,
                 const float* __restrict__ s2r,
                 const float* __restrict__ ow,  const float* __restrict__ ob,
                 float* __restrict__ out)
{
    __shared__ float nd[N_ * HID];
    __shared__ float agg[N_ * HID];
    __shared__ float g1[N_ * 64];
    __shared__ float agg2[N_ * 64];
    __shared__ float g2[N_ * 32];
    __shared__ float deg[N_];
    __shared__ float invdeg[N_];

    const int t = threadIdx.x;
    const int b = blockIdx.x;
    const int* esrc = edge;
    const int* edst = edge + E_;

    for (int i = t; i < N_ * HID; i += 256) {
        nd[i]  = nodes[(size_t)b * N_ * HID + i];
        agg[i] = 0.0f;
    }
    for (int i = t; i < N_; i += 256) deg[i] = 0.0f;
    __syncthreads();

    if (t < E_) atomicAdd(&deg[edst[t]], 1.0f);
    for (int i = t; i < E_ * HID; i += 256) {
        int e = i / HID, k = i % HID;
        atomicAdd(&agg[edst[e] * HID + k], nd[esrc[e] * HID + k]);
    }
    __syncthreads();
    for (int i = t; i < N_; i += 256) invdeg[i] = 1.0f / fmaxf(deg[i], 1.0f);
    __syncthreads();

    for (int idx = t; idx < N_ * 64; idx += 256) {
        int n = idx / 64, i = idx % 64;
        const float* lr = s1l + (size_t)i * HID;
        const float* rr = s1r + (size_t)i * HID;
        float id = invdeg[n];
        float acc = s1lb[i];
        for (int k = 0; k < HID; ++k)
            acc += lr[k] * (agg[n * HID + k] * id) + rr[k] * nd[n * HID + k];
        g1[idx] = fmaxf(acc, 0.0f);
    }
    __syncthreads();
    for (int i = t; i < N_ * 64; i += 256) agg2[i] = 0.0f;
    __syncthreads();
    for (int i = t; i < E_ * 64; i += 256) {
        int e = i / 64, k = i % 64;
        atomicAdd(&agg2[edst[e] * 64 + k], g1[esrc[e] * 64 + k]);
    }
    __syncthreads();

    for (int idx = t; idx < N_ * 32; idx += 256) {
        int n = idx / 32, i = idx % 32;
        const float* lr = s2l + (size_t)i * 64;
        const float* rr = s2r + (size_t)i * 64;
        float id = invdeg[n];
        float acc = s2lb[i];
        for (int k = 0; k < 64; ++k)
            acc += lr[k] * (agg2[n * 64 + k] * id) + rr[k] * g1[n * 64 + k];
        g2[idx] = fmaxf(acc, 0.0f);
    }
    __syncthreads();

    for (int idx = t; idx < N_ * 2; idx += 256) {
        int n = idx / 2, c = idx % 2;
        const float* wr = ow + (size_t)c * 32;
        float acc = ob[c];
        for (int k = 0; k < 32; ++k) acc += wr[k] * g2[n * 32 + k];
        out[((size_t)b * N_ + n) * 2 + c] = fmaxf(acc, 0.0f);
    }
}

extern "C" void kernel_launch(void* const* d_in, const int* in_sizes, int n_in,
                              void* d_out, int out_size, void* d_ws, size_t ws_size,
                              hipStream_t stream) {
    const float* X        = (const float*)d_in[0];
    const float* ts       = (const float*)d_in[1];
    const int*   edge     = (const int*)  d_in[2];
    const float* emb_pos  = (const float*)d_in[3];
    const float* emb_team = (const float*)d_in[4];
    const float* Wall_w   = (const float*)d_in[5];
    const float* Wall_b   = (const float*)d_in[6];
    const float* Uall_w   = (const float*)d_in[7];
    const float* Uall_b   = (const float*)d_in[8];
    const float* Wd_w     = (const float*)d_in[9];
    const float* Wd_b     = (const float*)d_in[10];
    const float* lin_w    = (const float*)d_in[11];
    const float* lin_b    = (const float*)d_in[12];
    const float* s1l      = (const float*)d_in[13];
    const float* s1lb     = (const float*)d_in[14];
    const float* s1r      = (const float*)d_in[15];
    const float* s2l      = (const float*)d_in[16];
    const float* s2lb     = (const float*)d_in[17];
    const float* s2r      = (const float*)d_in[18];
    const float* ow       = (const float*)d_in[19];
    const float* ob       = (const float*)d_in[20];

    float* nodes = (float*)d_ws;                                  // 2560*100*4 = 1,024,000 B
    float* Wcomb = (float*)((char*)d_ws + 1024000);               // 400*176*4  =   281,600 B
    float* WdT   = (float*)((char*)d_ws + 1024000 + 281600);      // 100*100*4  =    40,000 B

    const int repack_n = G4 * WSTR + HID * HID;
    repack_kernel<<<(repack_n + 255) / 256, 256, 0, stream>>>(Wall_w, Uall_w, Wd_w, Wcomb, WdT);

    lstm_kernel<<<NBLK, NTHR, 0, stream>>>(X, ts, emb_pos, emb_team,
                                           Wcomb, WdT, Wall_b, Uall_b, Wd_b,
                                           lin_w, lin_b, nodes);
    sage_kernel<<<B_, 256, 0, stream>>>(nodes, edge, s1l, s1lb, s1r,
                                        s2l, s2lb, s2r, ow, ob, (float*)d_out);
}

// Round 3
// 377.507 us; speedup vs baseline: 8.6314x; 5.9120x over previous
//
#include <hip/hip_runtime.h>
#include <math.h>

#define B_    64
#define W_    128
#define N_    40
#define FIN   66
#define HID   100
#define NEWD  71
#define MSEQ  10
#define NBLK  256   // 2560 / MSEQ
#define NTHR  1024  // 16 waves
#define E_    240

#define KG    192   // gate K padded (100 h + 71 xe + 21 pad)
#define KD    128   // decay K padded (100 c + 28 pad)
#define HXS   200   // hx row stride in shorts (16B-aligned, bank-spread: 400B)
#define CXS   136   // cx row stride in shorts (272B)
#define NGT   25    // gate m-tiles (25*16 = 400 rows)
#define NDT   7     // decay m-tiles (7*16 = 112 >= 100 rows)
#define NGU   150   // gate units  = 25 tiles * 6 kc
#define NU    178   // + decay units 7 tiles * 4 kc

typedef float  f32x4  __attribute__((ext_vector_type(4)));
typedef short  short8 __attribute__((ext_vector_type(8)));
typedef __bf16 bf16x8 __attribute__((ext_vector_type(8)));

__device__ __forceinline__ float sig_(float x) {
    return __builtin_amdgcn_rcpf(1.0f + __expf(-x));
}
__device__ __forceinline__ float tanh_(float x) {
    return fmaf(2.0f, __builtin_amdgcn_rcpf(1.0f + __expf(-2.0f * x)), -1.0f);
}
__device__ __forceinline__ unsigned short bf16_rne(float x) {
    unsigned u = __float_as_uint(x);
    unsigned r = u + 0x7FFFu + ((u >> 16) & 1u);
    return (unsigned short)(r >> 16);
}
__device__ __forceinline__ void bsplit(float x, short& hi, short& lo) {
    unsigned u = __float_as_uint(x);
    unsigned rh = u + 0x7FFFu + ((u >> 16) & 1u);
    unsigned short h = (unsigned short)(rh >> 16);
    float fh = __uint_as_float(((unsigned)h) << 16);
    float r = x - fh;
    unsigned u2 = __float_as_uint(r);
    unsigned rl = u2 + 0x7FFFu + ((u2 >> 16) & 1u);
    hi = (short)h;
    lo = (short)(rl >> 16);
}
__device__ __forceinline__ bf16x8 ldb(const short* p) {
    return __builtin_bit_cast(bf16x8, *(const short8*)p);
}

// ---------------------------------------------------------------------------
// Repack weights into pre-split bf16 A-fragments for mfma_f32_16x16x32_bf16.
// A-frag layout: lane l holds rows r=l&15, k = (l>>4)*8 + e (e=0..7).
// Gate unit u = T*6 + j: combined W row = [Wall (k<100) | Uall (100<=k<171) | 0].
// Decay unit u = 150 + D*4 + j: Wd row (pad rows/cols = 0).
// ---------------------------------------------------------------------------
__global__ void repack_kernel(const float* __restrict__ Wall_w,
                              const float* __restrict__ Uall_w,
                              const float* __restrict__ Wd_w,
                              unsigned short* __restrict__ Wfrag)
{
    int idx = blockIdx.x * 256 + threadIdx.x;   // (unit, lane)
    if (idx >= NU * 64) return;
    int u = idx >> 6, l = idx & 63;
    unsigned short v[8];
    #pragma unroll
    for (int e = 0; e < 8; ++e) {
        float wv = 0.0f;
        if (u < NGU) {
            int T = u / 6, j = u % 6;
            int R = T * 16 + (l & 15);
            int k = j * 32 + ((l >> 4) << 3) + e;
            if (k < 100)       wv = Wall_w[R * HID + k];
            else if (k < 171)  wv = Uall_w[R * NEWD + (k - 100)];
        } else {
            int du = u - NGU;
            int D = du / 4, j = du % 4;
            int R = D * 16 + (l & 15);
            int k = j * 32 + ((l >> 4) << 3) + e;
            if (R < 100 && k < 100) wv = Wd_w[R * HID + k];
        }
        v[e] = bf16_rne(wv);
    }
    unsigned short* dst = Wfrag + (size_t)idx * 8;
    #pragma unroll
    for (int e = 0; e < 8; ++e) dst[e] = v[e];
}

// ---------------------------------------------------------------------------
// LSTM kernel: 256 blocks x 1024 threads. MFMA recurrence.
// Wave slots: w<12: gate tiles {2w, 2w+1}; w==12: gate 24 + decay 0;
// w in 13..15: decay tiles {2(w-13)+1, 2(w-13)+2}.
// B operand (h/xe or c) lives in LDS as hi/lo bf16, rebuilt each step by the
// update threads (c,h carried in registers). Weights single-bf16 in VGPRs.
// Per step: [MFMA + prefetch-issue + C-scatter] bar [update + xe/ts write] bar
// ---------------------------------------------------------------------------
__global__ __launch_bounds__(NTHR, 4)
void lstm_kernel(const float* __restrict__ X, const float* __restrict__ ts,
                 const float* __restrict__ emb_pos, const float* __restrict__ emb_team,
                 const unsigned short* __restrict__ Wfrag,
                 const float* __restrict__ Wall_b, const float* __restrict__ Uall_b,
                 const float* __restrict__ Wd_b,
                 const float* __restrict__ lin_w,  const float* __restrict__ lin_b,
                 float* __restrict__ nodes)
{
    __shared__ short hxhi[16 * HXS];   // B for gates: [m][k] k:0..99 h, 100..170 xe
    __shared__ short hxlo[16 * HXS];
    __shared__ short cxhi[16 * CXS];   // B for decay: [m][k] k:0..99 c
    __shared__ short cxlo[16 * CXS];
    __shared__ float gts[NGT * 256];   // gate pre-activations [tile][row][col]
    __shared__ float dct[NDT * 256];   // decay pre-activations
    __shared__ float ts_s[2][16];

    const int t = threadIdx.x, l = t & 63, wv = t >> 6;
    const int r0 = blockIdx.x * MSEQ;

    // ---- zero B buffers (covers pad rows m>=10 and pad cols) ----
    for (int i = t; i < 16 * HXS; i += NTHR) { hxhi[i] = 0; hxlo[i] = 0; }
    for (int i = t; i < 16 * CXS; i += NTHR) { cxhi[i] = 0; cxlo[i] = 0; }

    // ---- wave slot config ----
    int typ0, til0, typ1, til1;          // 0 = gate, 1 = decay
    if (wv < 12)       { typ0 = 0; til0 = 2 * wv;          typ1 = 0; til1 = 2 * wv + 1; }
    else if (wv == 12) { typ0 = 0; til0 = 24;              typ1 = 1; til1 = 0; }
    else               { typ0 = 1; til0 = 2 * (wv - 13) + 1; typ1 = 1; til1 = 2 * (wv - 13) + 2; }
    const int ub0 = typ0 ? (NGU + til0 * 4) : (til0 * 6);
    const int ub1 = typ1 ? (NGU + til1 * 4) : (til1 * 6);

    // ---- persistent A-fragments ----
    bf16x8 af0[6], af1[6];
    if (wv < 12) {
        #pragma unroll
        for (int j = 0; j < 6; ++j) {
            af0[j] = __builtin_bit_cast(bf16x8, *(const short8*)(Wfrag + ((size_t)(ub0 + j) * 64 + l) * 8));
            af1[j] = __builtin_bit_cast(bf16x8, *(const short8*)(Wfrag + ((size_t)(ub1 + j) * 64 + l) * 8));
        }
    } else if (wv == 12) {
        #pragma unroll
        for (int j = 0; j < 6; ++j)
            af0[j] = __builtin_bit_cast(bf16x8, *(const short8*)(Wfrag + ((size_t)(ub0 + j) * 64 + l) * 8));
        #pragma unroll
        for (int j = 0; j < 4; ++j)
            af1[j] = __builtin_bit_cast(bf16x8, *(const short8*)(Wfrag + ((size_t)(ub1 + j) * 64 + l) * 8));
    } else {
        #pragma unroll
        for (int j = 0; j < 4; ++j) {
            af0[j] = __builtin_bit_cast(bf16x8, *(const short8*)(Wfrag + ((size_t)(ub0 + j) * 64 + l) * 8));
            af1[j] = __builtin_bit_cast(bf16x8, *(const short8*)(Wfrag + ((size_t)(ub1 + j) * 64 + l) * 8));
        }
    }

    // ---- update-thread constants ----
    const bool isUpd = (t < HID * MSEQ);
    const int ui = t / MSEQ, um = t % MSEQ;
    float bf_ = 0.f, bi_ = 0.f, bo_ = 0.f, bc_ = 0.f, bd_ = 0.f;
    int a_f = 0, a_i = 0, a_o = 0, a_c = 0, a_d = 0;
    if (isUpd) {
        bf_ = Wall_b[ui]       + Uall_b[ui];
        bi_ = Wall_b[ui + 100] + Uall_b[ui + 100];
        bo_ = Wall_b[ui + 200] + Uall_b[ui + 200];
        bc_ = Wall_b[ui + 300] + Uall_b[ui + 300];
        bd_ = Wd_b[ui];
        int jf = ui, ji = ui + 100, jo = ui + 200, jc = ui + 300;
        a_f = (jf >> 4) * 256 + (jf & 15) * 16 + um;
        a_i = (ji >> 4) * 256 + (ji & 15) * 16 + um;
        a_o = (jo >> 4) * 256 + (jo & 15) * 16 + um;
        a_c = (jc >> 4) * 256 + (jc & 15) * 16 + um;
        a_d = (ui >> 4) * 256 + (ui & 15) * 16 + um;
    }
    float creg = 0.0f, hreg = 0.0f;

    // ---- prefetch roles ----
    const float* xptr = nullptr;
    if (t < 640) {
        int m = t >> 6, f = t & 63;
        int r = r0 + m, b = r / N_, n = r % N_;
        xptr = X + ((size_t)b * W_ * N_ + n) * FIN + f;
    }
    const float* xcat = nullptr; const float* tsp = nullptr;
    int me = 0, mt = 0;
    if (t >= 1004 && t < 1014) {
        me = t - 1004;
        int r = r0 + me, b = r / N_, n = r % N_;
        xcat = X + ((size_t)b * W_ * N_ + n) * FIN;
    } else if (t >= 1014) {
        mt = t - 1014;
        int r = r0 + mt, b = r / N_, n = r % N_;
        tsp = ts + (size_t)b * W_ * N_ + n;
    }

    // ---- prologue: stage xe(0), ts(0) (h,c already zero) ----
    if (xptr) {
        float x0 = xptr[0];
        short hi, lo; bsplit(x0, hi, lo);
        int m = t >> 6, f = t & 63;
        hxhi[m * HXS + 100 + f] = hi; hxlo[m * HXS + 100 + f] = lo;
    }
    if (xcat) {
        float c0f = xcat[64], c1f = xcat[65];
        int ip = (int)c0f, itm = (int)c1f;
        int sp = ip > 0 ? ip - 1 : 0;   float fp  = ip > 0 ? 1.f : 0.f;
        int st = itm > 0 ? itm - 1 : 0; float ft_ = itm > 0 ? 1.f : 0.f;
        #pragma unroll
        for (int q = 0; q < 4; ++q) {
            short hi, lo; bsplit(emb_pos[sp * 4 + q] * fp, hi, lo);
            hxhi[me * HXS + 164 + q] = hi; hxlo[me * HXS + 164 + q] = lo;
        }
        #pragma unroll
        for (int q = 0; q < 3; ++q) {
            short hi, lo; bsplit(emb_team[st * 3 + q] * ft_, hi, lo);
            hxhi[me * HXS + 168 + q] = hi; hxlo[me * HXS + 168 + q] = lo;
        }
    }
    if (tsp) ts_s[0][mt] = tsp[0];
    __syncthreads();

    // ---- main loop ----
    for (int step = 0; step < W_; ++step) {
        const int cur = step & 1, nxt = cur ^ 1;
        const bool pf = (step + 1 < W_);

        // prefetch issue (consumed after barrier; latency hides under MFMA)
        float xv = 0.f, c0f = 0.f, c1f = 0.f, tv = 0.f;
        if (pf) {
            const size_t off = (size_t)(step + 1) * (N_ * FIN);
            if (xptr) xv = xptr[off];
            if (xcat) { c0f = xcat[off + 64]; c1f = xcat[off + 65]; }
            if (tsp)  tv = tsp[(size_t)(step + 1) * N_];
        }

        // ===== MFMA phase =====
        f32x4 acc0 = {0.f, 0.f, 0.f, 0.f}, acc1 = {0.f, 0.f, 0.f, 0.f};
        if (wv < 12) {
            const int ba = (l & 15) * HXS + ((l >> 4) << 3);
            #pragma unroll
            for (int j = 0; j < 6; ++j) {
                bf16x8 bh = ldb(&hxhi[ba + j * 32]);
                bf16x8 bl = ldb(&hxlo[ba + j * 32]);
                acc0 = __builtin_amdgcn_mfma_f32_16x16x32_bf16(af0[j], bh, acc0, 0, 0, 0);
                acc0 = __builtin_amdgcn_mfma_f32_16x16x32_bf16(af0[j], bl, acc0, 0, 0, 0);
                acc1 = __builtin_amdgcn_mfma_f32_16x16x32_bf16(af1[j], bh, acc1, 0, 0, 0);
                acc1 = __builtin_amdgcn_mfma_f32_16x16x32_bf16(af1[j], bl, acc1, 0, 0, 0);
            }
        } else if (wv == 12) {
            const int ba = (l & 15) * HXS + ((l >> 4) << 3);
            #pragma unroll
            for (int j = 0; j < 6; ++j) {
                bf16x8 bh = ldb(&hxhi[ba + j * 32]);
                bf16x8 bl = ldb(&hxlo[ba + j * 32]);
                acc0 = __builtin_amdgcn_mfma_f32_16x16x32_bf16(af0[j], bh, acc0, 0, 0, 0);
                acc0 = __builtin_amdgcn_mfma_f32_16x16x32_bf16(af0[j], bl, acc0, 0, 0, 0);
            }
            const int bc = (l & 15) * CXS + ((l >> 4) << 3);
            #pragma unroll
            for (int j = 0; j < 4; ++j) {
                bf16x8 bh = ldb(&cxhi[bc + j * 32]);
                bf16x8 bl = ldb(&cxlo[bc + j * 32]);
                acc1 = __builtin_amdgcn_mfma_f32_16x16x32_bf16(af1[j], bh, acc1, 0, 0, 0);
                acc1 = __builtin_amdgcn_mfma_f32_16x16x32_bf16(af1[j], bl, acc1, 0, 0, 0);
            }
        } else {
            const int bc = (l & 15) * CXS + ((l >> 4) << 3);
            #pragma unroll
            for (int j = 0; j < 4; ++j) {
                bf16x8 bh = ldb(&cxhi[bc + j * 32]);
                bf16x8 bl = ldb(&cxlo[bc + j * 32]);
                acc0 = __builtin_amdgcn_mfma_f32_16x16x32_bf16(af0[j], bh, acc0, 0, 0, 0);
                acc0 = __builtin_amdgcn_mfma_f32_16x16x32_bf16(af0[j], bl, acc0, 0, 0, 0);
                acc1 = __builtin_amdgcn_mfma_f32_16x16x32_bf16(af1[j], bh, acc1, 0, 0, 0);
                acc1 = __builtin_amdgcn_mfma_f32_16x16x32_bf16(af1[j], bl, acc1, 0, 0, 0);
            }
        }
        // C scatter (verified layout: col = lane&15, row = (lane>>4)*4 + q)
        {
            float* d0 = typ0 ? &dct[til0 * 256] : &gts[til0 * 256];
            float* d1 = typ1 ? &dct[til1 * 256] : &gts[til1 * 256];
            const int so = ((l >> 4) << 6) + (l & 15);
            #pragma unroll
            for (int q = 0; q < 4; ++q) {
                d0[so + q * 16] = acc0[q];
                d1[so + q * 16] = acc1[q];
            }
        }
        __syncthreads();

        // ===== update phase =====
        if (isUpd) {
            float gf  = sig_(gts[a_f] + bf_);
            float gi  = sig_(gts[a_i] + bi_);
            float go  = sig_(gts[a_o] + bo_);
            float gc  = sig_(gts[a_c] + bc_);
            float cs1 = tanh_(dct[a_d] + bd_);
            float tsv = ts_s[cur][um];
            float cadj = fmaf(cs1, tsv - 1.0f, creg);
            float cn = gf * cadj + gi * gc;
            creg = cn;
            hreg = go * tanh_(cn);
            short hi, lo;
            bsplit(hreg, hi, lo); hxhi[um * HXS + ui] = hi; hxlo[um * HXS + ui] = lo;
            bsplit(cn,   hi, lo); cxhi[um * CXS + ui] = hi; cxlo[um * CXS + ui] = lo;
        }
        if (pf) {
            if (xptr) {
                short hi, lo; bsplit(xv, hi, lo);
                int m = t >> 6, f = t & 63;
                hxhi[m * HXS + 100 + f] = hi; hxlo[m * HXS + 100 + f] = lo;
            }
            if (xcat) {
                int ip = (int)c0f, itm = (int)c1f;
                int sp = ip > 0 ? ip - 1 : 0;   float fp  = ip > 0 ? 1.f : 0.f;
                int st = itm > 0 ? itm - 1 : 0; float ft_ = itm > 0 ? 1.f : 0.f;
                #pragma unroll
                for (int q = 0; q < 4; ++q) {
                    short hi, lo; bsplit(emb_pos[sp * 4 + q] * fp, hi, lo);
                    hxhi[me * HXS + 164 + q] = hi; hxlo[me * HXS + 164 + q] = lo;
                }
                #pragma unroll
                for (int q = 0; q < 3; ++q) {
                    short hi, lo; bsplit(emb_team[st * 3 + q] * ft_, hi, lo);
                    hxhi[me * HXS + 168 + q] = hi; hxlo[me * HXS + 168 + q] = lo;
                }
            }
            if (tsp) ts_s[nxt][mt] = tv;
        }
        __syncthreads();
    }

    // ---- lin head: nodes = relu(h @ lin_w^T + lin_b) ----
    if (isUpd) gts[ui * MSEQ + um] = hreg;   // reuse gts as hfin[k][m]
    __syncthreads();
    if (isUpd) {
        const float* lr = lin_w + (size_t)ui * HID;
        float acc = lin_b[ui];
        for (int k = 0; k < HID; ++k) acc = fmaf(lr[k], gts[k * MSEQ + um], acc);
        nodes[(size_t)(r0 + um) * HID + ui] = fmaxf(acc, 0.0f);
    }
}

// ---------------------------------------------------------------------------
// Kernel B: per-batch GraphSAGE x2 + output head, all in LDS. (unchanged)
// ---------------------------------------------------------------------------
__global__ __launch_bounds__(256, 1)
void sage_kernel(const float* __restrict__ nodes, const int* __restrict__ edge,
                 const float* __restrict__ s1l, const float* __restrict__ s1lb,
                 const float* __restrict__ s1r,
                 const float* __restrict__ s2l, const float* __restrict__ s2lb,
                 const float* __restrict__ s2r,
                 const float* __restrict__ ow,  const float* __restrict__ ob,
                 float* __restrict__ out)
{
    __shared__ float nd[N_ * HID];
    __shared__ float agg[N_ * HID];
    __shared__ float g1[N_ * 64];
    __shared__ float agg2[N_ * 64];
    __shared__ float g2[N_ * 32];
    __shared__ float deg[N_];
    __shared__ float invdeg[N_];

    const int t = threadIdx.x;
    const int b = blockIdx.x;
    const int* esrc = edge;
    const int* edst = edge + E_;

    for (int i = t; i < N_ * HID; i += 256) {
        nd[i]  = nodes[(size_t)b * N_ * HID + i];
        agg[i] = 0.0f;
    }
    for (int i = t; i < N_; i += 256) deg[i] = 0.0f;
    __syncthreads();

    if (t < E_) atomicAdd(&deg[edst[t]], 1.0f);
    for (int i = t; i < E_ * HID; i += 256) {
        int e = i / HID, k = i % HID;
        atomicAdd(&agg[edst[e] * HID + k], nd[esrc[e] * HID + k]);
    }
    __syncthreads();
    for (int i = t; i < N_; i += 256) invdeg[i] = 1.0f / fmaxf(deg[i], 1.0f);
    __syncthreads();

    for (int idx = t; idx < N_ * 64; idx += 256) {
        int n = idx / 64, i = idx % 64;
        const float* lr = s1l + (size_t)i * HID;
        const float* rr = s1r + (size_t)i * HID;
        float id = invdeg[n];
        float acc = s1lb[i];
        for (int k = 0; k < HID; ++k)
            acc += lr[k] * (agg[n * HID + k] * id) + rr[k] * nd[n * HID + k];
        g1[idx] = fmaxf(acc, 0.0f);
    }
    __syncthreads();
    for (int i = t; i < N_ * 64; i += 256) agg2[i] = 0.0f;
    __syncthreads();
    for (int i = t; i < E_ * 64; i += 256) {
        int e = i / 64, k = i % 64;
        atomicAdd(&agg2[edst[e] * 64 + k], g1[esrc[e] * 64 + k]);
    }
    __syncthreads();

    for (int idx = t; idx < N_ * 32; idx += 256) {
        int n = idx / 32, i = idx % 32;
        const float* lr = s2l + (size_t)i * 64;
        const float* rr = s2r + (size_t)i * 64;
        float id = invdeg[n];
        float acc = s2lb[i];
        for (int k = 0; k < 64; ++k)
            acc += lr[k] * (agg2[n * 64 + k] * id) + rr[k] * g1[n * 64 + k];
        g2[idx] = fmaxf(acc, 0.0f);
    }
    __syncthreads();

    for (int idx = t; idx < N_ * 2; idx += 256) {
        int n = idx / 2, c = idx % 2;
        const float* wr = ow + (size_t)c * 32;
        float acc = ob[c];
        for (int k = 0; k < 32; ++k) acc += wr[k] * g2[n * 32 + k];
        out[((size_t)b * N_ + n) * 2 + c] = fmaxf(acc, 0.0f);
    }
}

extern "C" void kernel_launch(void* const* d_in, const int* in_sizes, int n_in,
                              void* d_out, int out_size, void* d_ws, size_t ws_size,
                              hipStream_t stream) {
    const float* X        = (const float*)d_in[0];
    const float* ts       = (const float*)d_in[1];
    const int*   edge     = (const int*)  d_in[2];
    const float* emb_pos  = (const float*)d_in[3];
    const float* emb_team = (const float*)d_in[4];
    const float* Wall_w   = (const float*)d_in[5];
    const float* Wall_b   = (const float*)d_in[6];
    const float* Uall_w   = (const float*)d_in[7];
    const float* Uall_b   = (const float*)d_in[8];
    const float* Wd_w     = (const float*)d_in[9];
    const float* Wd_b     = (const float*)d_in[10];
    const float* lin_w    = (const float*)d_in[11];
    const float* lin_b    = (const float*)d_in[12];
    const float* s1l      = (const float*)d_in[13];
    const float* s1lb     = (const float*)d_in[14];
    const float* s1r      = (const float*)d_in[15];
    const float* s2l      = (const float*)d_in[16];
    const float* s2lb     = (const float*)d_in[17];
    const float* s2r      = (const float*)d_in[18];
    const float* ow       = (const float*)d_in[19];
    const float* ob       = (const float*)d_in[20];

    float*          nodes = (float*)d_ws;                          // 1,024,000 B
    unsigned short* Wfrag = (unsigned short*)((char*)d_ws + 1024000); // 178*64*8*2 = 182,272 B

    repack_kernel<<<(NU * 64 + 255) / 256, 256, 0, stream>>>(Wall_w, Uall_w, Wd_w, Wfrag);

    lstm_kernel<<<NBLK, NTHR, 0, stream>>>(X, ts, emb_pos, emb_team, Wfrag,
                                           Wall_b, Uall_b, Wd_b,
                                           lin_w, lin_b, nodes);
    sage_kernel<<<B_, 256, 0, stream>>>(nodes, edge, s1l, s1lb, s1r,
                                        s2l, s2lb, s2r, ow, ob, (float*)d_out);
}